// Round 9
// baseline (147.511 us; speedup 1.0000x reference)
//
#include <hip/hip_runtime.h>
#include <hip/hip_bf16.h>

#define NN 50000
#define NE 800000
#define NPAD 50048   // rows padded to multiple of 64
#define NBK 512      // coarse buckets for CSR build
#define RNG 98       // nodes per bucket (512*98 = 50176 >= NN)
#define BCAP 2560    // bucket capacity (mean 1568, +25 sigma)
#define CSTRIDE 16   // cursor padding: 1 cursor per 64B line
#define EPB 4096     // edges per block in bucket fill
#define NFB ((NE + EPB - 1) / EPB)   // 196 blocks
#define CSRCAP 1536  // per-64-node-block CSR window (mean 1024)
#define GB (NPAD / 64)               // 782 row-blocks

typedef __attribute__((ext_vector_type(8))) short bf8;       // 8 bf16 = 4 VGPR
typedef __attribute__((ext_vector_type(4))) float f4;
typedef __attribute__((ext_vector_type(2))) float f2v;
typedef __attribute__((ext_vector_type(4))) unsigned int u4v; // 16B
typedef __attribute__((ext_vector_type(2))) unsigned int u2v; // 8B

__device__ __forceinline__ unsigned short f2bf(float f) {  // RNE
    union { float f; unsigned int u; } x; x.f = f;
    unsigned int r = x.u + 0x7fffu + ((x.u >> 16) & 1u);
    return (unsigned short)(r >> 16);
}
__device__ __forceinline__ float b2f(short s) {
    union { unsigned int u; float f; } x;
    x.u = ((unsigned int)(unsigned short)s) << 16;
    return x.f;
}
__device__ __forceinline__ unsigned char f2fp8(float v) {  // e4m3 (OCP), RNE
    return (unsigned char)(__builtin_amdgcn_cvt_pk_fp8_f32(v, v, 0, false) & 0xff);
}
// accumulate 16 fp8 (one 16B vector) into acc[0..15]
__device__ __forceinline__ void acc16_fp8(float* acc, u4v v) {
    #pragma unroll
    for (int t = 0; t < 4; ++t) {
        f2v lo = __builtin_amdgcn_cvt_pk_f32_fp8((int)v[t], false);
        f2v hi = __builtin_amdgcn_cvt_pk_f32_fp8((int)v[t], true);
        acc[t * 4 + 0] += lo.x; acc[t * 4 + 1] += lo.y;
        acc[t * 4 + 2] += hi.x; acc[t * 4 + 3] += hi.y;
    }
}
// accumulate 8 fp8 (one 8B vector) into acc[0..7]
__device__ __forceinline__ void acc8_fp8(float* acc, u2v v) {
    #pragma unroll
    for (int t = 0; t < 2; ++t) {
        f2v lo = __builtin_amdgcn_cvt_pk_f32_fp8((int)v[t], false);
        f2v hi = __builtin_amdgcn_cvt_pk_f32_fp8((int)v[t], true);
        acc[t * 4 + 0] += lo.x; acc[t * 4 + 1] += lo.y;
        acc[t * 4 + 2] += hi.x; acc[t * 4 + 3] += hi.y;
    }
}

// ---------------- launch 1: zero bucket cursors ----------------
__global__ void zero_k(int* __restrict__ cursor, int* __restrict__ rowptr) {
    cursor[threadIdx.x * CSTRIDE] = 0;
    if (threadIdx.x == 0) rowptr[NN] = NE;
}

// ---------------- launch 2: bucket fill (blocks 0..NFB-1) || pack weights ----------------
__global__ __launch_bounds__(256) void prep_k(const int* __restrict__ ei,
                                              int* __restrict__ cursor,
                                              unsigned int* __restrict__ bucket,
                                              const float* __restrict__ Wl0, const float* __restrict__ Wr0,
                                              const float* __restrict__ Wl1, const float* __restrict__ Wr1,
                                              const float* __restrict__ Wl2, const float* __restrict__ Wr2,
                                              unsigned short* __restrict__ Bp) {
    __shared__ unsigned int sorted[EPB];
    __shared__ unsigned short sbuck[EPB];
    __shared__ int hist[NBK], ofs[NBK], gpos[NBK], stmp[256];
    const int tid = threadIdx.x;
    if (blockIdx.x >= NFB) {
        int idx = (blockIdx.x - NFB) * 256 + tid;
        const float *Wl, *Wr;
        int Mo, local;
        unsigned short* out;
        if (idx < 32768)       { Wl = Wl0; Wr = Wr0; Mo = 128; out = Bp;         local = idx; }
        else if (idx < 65536)  { Wl = Wl1; Wr = Wr1; Mo = 128; out = Bp + 32768; local = idx - 32768; }
        else if (idx < 81920)  { Wl = Wl2; Wr = Wr2; Mo = 64;  out = Bp + 65536; local = idx - 65536; }
        else return;
        int ncol = 2 * Mo;
        int k = local / ncol, c = local % ncol;
        float v = (c < Mo) ? Wl[k * Mo + c] : Wr[k * Mo + (c - Mo)];
        int cf = c >> 4, ks = k >> 5;
        int lane = (c & 15) | (((k & 31) >> 3) << 4);
        int i = k & 7;
        out[(((cf << 2) | ks) * 64 + lane) * 8 + i] = f2bf(v);
        return;
    }
    const int e0 = blockIdx.x * EPB;
    const int n = (NE - e0) < EPB ? (NE - e0) : EPB;

    for (int i = tid; i < NBK; i += 256) hist[i] = 0;
    __syncthreads();

    unsigned int ent[EPB / 256];
    short bks[EPB / 256];
    #pragma unroll
    for (int j = 0; j < EPB / 256; ++j) {
        const int li = tid + j * 256;
        int b = -1; unsigned v = 0;
        if (li < n) {
            const int e = e0 + li;
            const int s = ei[e];
            const int d = ei[NE + e];
            b = d / RNG;
            v = (unsigned)s | ((unsigned)(d - b * RNG) << 16);
            atomicAdd(&hist[b], 1);
        }
        ent[j] = v; bks[j] = (short)b;
    }
    __syncthreads();

    const int p0 = hist[2 * tid], p1 = hist[2 * tid + 1];
    stmp[tid] = p0 + p1;
    __syncthreads();
    #pragma unroll
    for (int off = 1; off < 256; off <<= 1) {
        const int t = (tid >= off) ? stmp[tid - off] : 0;
        __syncthreads();
        stmp[tid] += t;
        __syncthreads();
    }
    const int pbase = stmp[tid] - p0 - p1;
    ofs[2 * tid] = pbase;
    ofs[2 * tid + 1] = pbase + p0;
    __syncthreads();

    for (int i = tid; i < NBK; i += 256) {
        const int c = hist[i];
        gpos[i] = c ? atomicAdd(&cursor[i * CSTRIDE], c) : 0;
    }
    for (int i = tid; i < NBK; i += 256) hist[i] = ofs[i];
    __syncthreads();
    #pragma unroll
    for (int j = 0; j < EPB / 256; ++j) {
        if (bks[j] >= 0) {
            const int r = atomicAdd(&hist[(int)bks[j]], 1);
            sorted[r] = ent[j];
            sbuck[r] = (unsigned short)bks[j];
        }
    }
    __syncthreads();
    for (int i = tid; i < n; i += 256) {
        const int b = sbuck[i];
        const int idx = gpos[b] + (i - ofs[b]);
        if (idx < BCAP) bucket[(size_t)b * BCAP + idx] = sorted[i];
    }
}

// ---------------- launch 3: csr_build (blocks 0..511) || layer-1 GEMM from fp32 x ----------------
// GEMM epilogue: cols 0..127 -> Yq (fp8), cols 128..255 -> Z (bf16)
__global__ __launch_bounds__(256) void mid_k(const unsigned int* __restrict__ bucket,
                                             const int* __restrict__ cursor,
                                             int* __restrict__ rowptr, int* __restrict__ csr,
                                             const float* __restrict__ x,
                                             const unsigned short* __restrict__ Bp,
                                             unsigned char* __restrict__ Yq,
                                             unsigned short* __restrict__ Z) {
    __shared__ unsigned int ent[BCAP];
    __shared__ int hist[RNG], lcur[RNG], sofs[NBK], stmp[256];
    const int tid = threadIdx.x;
    if (blockIdx.x < NBK) {
        const int b = blockIdx.x;
        const int c0 = cursor[(2 * tid) * CSTRIDE];
        const int c1 = cursor[(2 * tid + 1) * CSTRIDE];
        stmp[tid] = c0 + c1;
        __syncthreads();
        #pragma unroll
        for (int off = 1; off < 256; off <<= 1) {
            const int t = (tid >= off) ? stmp[tid - off] : 0;
            __syncthreads();
            stmp[tid] += t;
            __syncthreads();
        }
        const int pbase = stmp[tid] - c0 - c1;
        sofs[2 * tid] = pbase;
        sofs[2 * tid + 1] = pbase + c0;
        for (int i = tid; i < RNG; i += 256) { hist[i] = 0; lcur[i] = 0; }
        __syncthreads();

        const int sz0 = cursor[b * CSTRIDE];
        const int sz = sz0 < BCAP ? sz0 : BCAP;
        const int gbase = sofs[b];
        for (int i = tid; i < sz; i += 256) {
            unsigned v = bucket[(size_t)b * BCAP + i];
            ent[i] = v;
            atomicAdd(&hist[v >> 16], 1);
        }
        __syncthreads();
        if (tid == 0) {
            int acc = 0;
            #pragma unroll 2
            for (int i = 0; i < RNG; ++i) { int c = hist[i]; hist[i] = acc; acc += c; }
        }
        __syncthreads();
        const int n0 = b * RNG;
        for (int i = tid; i < RNG; i += 256) {
            int nn = n0 + i;
            if (nn < NN) rowptr[nn] = gbase + hist[i];
        }
        for (int i = tid; i < sz; i += 256) {
            unsigned v = ent[i];
            int dloc = v >> 16;
            int r = atomicAdd(&lcur[dloc], 1);
            csr[gbase + hist[dloc] + r] = (int)(v & 0xffffu);
        }
        return;
    }
    // ---- layer-1 dual GEMM ----
    const int wave = tid >> 6;
    const int lane = tid & 63;
    const int r0 = (blockIdx.x - NBK) * 64;

    bf8 bfr[4][4];
    const bf8* bp = reinterpret_cast<const bf8*>(Bp);
    #pragma unroll
    for (int cf = 0; cf < 4; ++cf)
        #pragma unroll
        for (int ks = 0; ks < 4; ++ks)
            bfr[cf][ks] = bp[((wave * 4 + cf) * 4 + ks) * 64 + lane];

    const int rlane = lane & 15, kc = lane >> 4;
    #pragma unroll
    for (int rf = 0; rf < 4; ++rf) {
        const int arow = r0 + rf * 16 + rlane;
        const bool ok = arow < NN;
        const float4* ap = reinterpret_cast<const float4*>(x + (size_t)arow * 128);
        bf8 afr[4];
        #pragma unroll
        for (int ks = 0; ks < 4; ++ks) {
            float4 a0 = make_float4(0.f,0.f,0.f,0.f), a1 = a0;
            if (ok) { a0 = ap[ks * 8 + kc * 2]; a1 = ap[ks * 8 + kc * 2 + 1]; }
            bf8 t;
            t[0]=(short)f2bf(a0.x); t[1]=(short)f2bf(a0.y); t[2]=(short)f2bf(a0.z); t[3]=(short)f2bf(a0.w);
            t[4]=(short)f2bf(a1.x); t[5]=(short)f2bf(a1.y); t[6]=(short)f2bf(a1.z); t[7]=(short)f2bf(a1.w);
            afr[ks] = t;
        }
        f4 acc[4];
        #pragma unroll
        for (int cf = 0; cf < 4; ++cf) acc[cf] = (f4){0.f, 0.f, 0.f, 0.f};
        #pragma unroll
        for (int ks = 0; ks < 4; ++ks)
            #pragma unroll
            for (int cf = 0; cf < 4; ++cf)
                acc[cf] = __builtin_amdgcn_mfma_f32_16x16x32_bf16(afr[ks], bfr[cf][ks], acc[cf], 0, 0, 0);
        const int orow0 = r0 + rf * 16 + (lane >> 4) * 4;
        #pragma unroll
        for (int j = 0; j < 4; ++j) {
            const int orow = orow0 + j;
            if (orow < NN) {
                #pragma unroll
                for (int cf = 0; cf < 4; ++cf) {
                    const int col = (wave * 4 + cf) * 16 + rlane;
                    const float v = acc[cf][j];
                    if (col < 128) Yq[(size_t)orow * 128 + col] = f2fp8(v);
                    else           Z[(size_t)orow * 128 + (col - 128)] = f2bf(v);
                }
            }
        }
    }
}

// ---------------- launches 4,5: fused gather+combine+ELU+GEMM (512 threads, 8 waves) ----------------
// Inputs: Yq_in [NPAD][128] fp8, Z_in [NPAD][128] bf16.
// Phase A: 8 lanes/node, 16 fp8 cols each (1x16B load per edge); 8-edge unroll.
// Phase B: dual GEMM, col-frags split across 8 waves; cols<MOUT -> Yq_out fp8, else Z_out bf16
template<int MOUT>
__global__ __launch_bounds__(512) void fused_k(const int* __restrict__ rowptr,
                                               const int* __restrict__ csr,
                                               const unsigned char* __restrict__ Yq_in,
                                               const unsigned short* __restrict__ Z_in,
                                               const float* __restrict__ bias,
                                               const unsigned short* __restrict__ Bp,
                                               unsigned char* __restrict__ Yq_out,
                                               unsigned short* __restrict__ Z_out) {
    constexpr int CFT = 2 * MOUT / 16;     // total col-frags (16 or 8)
    constexpr int CFW = CFT / 8;           // col-frags per wave (2 or 1)
    __shared__ int lcsr[CSRCAP];
    __shared__ unsigned short tile[64 * 128];  // XOR-swizzled: byte ^= (row&7)<<4
    const int tid = threadIdx.x;
    const int n0 = blockIdx.x * 64;
    const int nend = (n0 + 64 > NN) ? NN : (n0 + 64);
    const int beg0 = rowptr[n0];
    const int tot = rowptr[nend] - beg0;
    const bool inlds = tot <= CSRCAP;
    if (inlds) for (int i = tid; i < tot; i += 512) lcsr[i] = csr[beg0 + i];
    __syncthreads();

    // ---- phase A: gather ----
    const int g = tid >> 3, l = tid & 7;   // node-in-block, lane-in-node (16 cols each)
    const int node = n0 + g;
    char* tbase = reinterpret_cast<char*>(tile);
    if (node < NN) {
        const int beg = rowptr[node], end = rowptr[node + 1];
        float acc[16];
        #pragma unroll
        for (int i = 0; i < 16; ++i) acc[i] = 0.f;
        int e = beg;
        for (; e + 8 <= end; e += 8) {     // 8 independent 16B lines in flight
            int ss[8];
            #pragma unroll
            for (int j = 0; j < 8; ++j) ss[j] = inlds ? lcsr[e + j - beg0] : csr[e + j];
            u4v u[8];
            #pragma unroll
            for (int j = 0; j < 8; ++j)
                u[j] = *reinterpret_cast<const u4v*>(Yq_in + (size_t)ss[j] * 128 + l * 16);
            #pragma unroll
            for (int j = 0; j < 8; ++j) acc16_fp8(acc, u[j]);
        }
        for (; e + 4 <= end; e += 4) {
            int ss[4];
            #pragma unroll
            for (int j = 0; j < 4; ++j) ss[j] = inlds ? lcsr[e + j - beg0] : csr[e + j];
            u4v u[4];
            #pragma unroll
            for (int j = 0; j < 4; ++j)
                u[j] = *reinterpret_cast<const u4v*>(Yq_in + (size_t)ss[j] * 128 + l * 16);
            #pragma unroll
            for (int j = 0; j < 4; ++j) acc16_fp8(acc, u[j]);
        }
        for (; e < end; ++e) {
            const int s0 = inlds ? lcsr[e - beg0] : csr[e];
            acc16_fp8(acc, *reinterpret_cast<const u4v*>(Yq_in + (size_t)s0 * 128 + l * 16));
        }
        const float invd = 1.0f / fmaxf((float)(end - beg), 1.0f);
        const bf8* zp = reinterpret_cast<const bf8*>(&Z_in[(size_t)node * 128 + l * 16]);
        const float* bp = bias + l * 16;
        #pragma unroll
        for (int c8 = 0; c8 < 2; ++c8) {
            const bf8 z = zp[c8];
            bf8 o;
            #pragma unroll
            for (int i = 0; i < 8; ++i) {
                float h = acc[c8 * 8 + i] * invd + b2f(z[i]) + bp[c8 * 8 + i];
                h = h > 0.f ? h : expf(h) - 1.f;  // ELU
                o[i] = (short)f2bf(h);
            }
            const unsigned byte = (unsigned)((g * 256 + l * 32 + c8 * 16) ^ ((g & 7) << 4));
            *reinterpret_cast<bf8*>(tbase + byte) = o;
        }
    } else {
        const bf8 zz = (bf8){0,0,0,0,0,0,0,0};
        #pragma unroll
        for (int c8 = 0; c8 < 2; ++c8) {
            const unsigned byte = (unsigned)((g * 256 + l * 32 + c8 * 16) ^ ((g & 7) << 4));
            *reinterpret_cast<bf8*>(tbase + byte) = zz;
        }
    }

    // ---- phase B: dual GEMM from LDS tile (8 waves x CFW col-frags) ----
    const int wave = tid >> 6;
    const int lane = tid & 63;
    bf8 bfr[CFW][4];
    const bf8* bpf = reinterpret_cast<const bf8*>(Bp);
    #pragma unroll
    for (int cf = 0; cf < CFW; ++cf)
        #pragma unroll
        for (int ks = 0; ks < 4; ++ks)
            bfr[cf][ks] = bpf[((wave * CFW + cf) * 4 + ks) * 64 + lane];
    __syncthreads();

    const int rlane = lane & 15, kc = lane >> 4;
    #pragma unroll
    for (int rf = 0; rf < 4; ++rf) {
        const int row = rf * 16 + rlane;
        bf8 afr[4];
        #pragma unroll
        for (int ks = 0; ks < 4; ++ks) {
            const unsigned byte = (unsigned)((row * 256 + ks * 64 + kc * 16) ^ ((row & 7) << 4));
            afr[ks] = *reinterpret_cast<const bf8*>(tbase + byte);
        }
        f4 acc[CFW];
        #pragma unroll
        for (int cf = 0; cf < CFW; ++cf) acc[cf] = (f4){0.f, 0.f, 0.f, 0.f};
        #pragma unroll
        for (int ks = 0; ks < 4; ++ks)
            #pragma unroll
            for (int cf = 0; cf < CFW; ++cf)
                acc[cf] = __builtin_amdgcn_mfma_f32_16x16x32_bf16(afr[ks], bfr[cf][ks], acc[cf], 0, 0, 0);
        const int orow0 = n0 + rf * 16 + (lane >> 4) * 4;
        #pragma unroll
        for (int j = 0; j < 4; ++j) {
            const int orow = orow0 + j;
            if (orow < NN) {
                #pragma unroll
                for (int cf = 0; cf < CFW; ++cf) {
                    const int col = (wave * CFW + cf) * 16 + rlane;
                    const float v = acc[cf][j];
                    if (col < MOUT) Yq_out[(size_t)orow * MOUT + col] = f2fp8(v);
                    else            Z_out[(size_t)orow * MOUT + (col - MOUT)] = f2bf(v);
                }
            }
        }
    }
}

// ---------------- launch 6: final gather + combine + log_softmax (512 threads) ----------------
// Yq2 [NPAD][64] fp8, Z2 [NPAD][64] bf16; 8 lanes/node, 8 cols each (8B loads)
__global__ __launch_bounds__(512) void gathlsm_k(const int* __restrict__ rowptr,
                                                 const int* __restrict__ csr,
                                                 const unsigned char* __restrict__ Yq2,
                                                 const unsigned short* __restrict__ Z2,
                                                 const float* __restrict__ bias,
                                                 float* __restrict__ lout) {
    __shared__ int lcsr[CSRCAP];
    const int tid = threadIdx.x;
    const int n0 = blockIdx.x * 64;
    const int nend = (n0 + 64 > NN) ? NN : (n0 + 64);
    const int beg0 = rowptr[n0];
    const int tot = rowptr[nend] - beg0;
    const bool inlds = tot <= CSRCAP;
    if (inlds) for (int i = tid; i < tot; i += 512) lcsr[i] = csr[beg0 + i];
    __syncthreads();

    const int g = tid >> 3, l = tid & 7;   // 64 nodes/block, 8 cols/lane
    const int n = n0 + g;
    if (n >= NN) return;
    const int beg = rowptr[n], end = rowptr[n + 1];

    float acc[8];
    #pragma unroll
    for (int i = 0; i < 8; ++i) acc[i] = 0.f;
    int e = beg;
    for (; e + 8 <= end; e += 8) {   // 8 lines in flight/lane
        int ss[8];
        #pragma unroll
        for (int j = 0; j < 8; ++j) ss[j] = inlds ? lcsr[e + j - beg0] : csr[e + j];
        u2v u[8];
        #pragma unroll
        for (int j = 0; j < 8; ++j)
            u[j] = *reinterpret_cast<const u2v*>(Yq2 + (size_t)ss[j] * 64 + l * 8);
        #pragma unroll
        for (int j = 0; j < 8; ++j) acc8_fp8(acc, u[j]);
    }
    for (; e < end; ++e) {
        const int s0 = inlds ? lcsr[e - beg0] : csr[e];
        acc8_fp8(acc, *reinterpret_cast<const u2v*>(Yq2 + (size_t)s0 * 64 + l * 8));
    }
    const float inv = 1.0f / fmaxf((float)(end - beg), 1.0f);
    const bf8 z = *reinterpret_cast<const bf8*>(&Z2[(size_t)n * 64 + l * 8]);
    float h[8];
    #pragma unroll
    for (int i = 0; i < 8; ++i) h[i] = acc[i] * inv + b2f(z[i]) + bias[l * 8 + i];

    float m = h[0];
    #pragma unroll
    for (int i = 1; i < 8; ++i) m = fmaxf(m, h[i]);
    m = fmaxf(m, __shfl_xor(m, 1, 64));
    m = fmaxf(m, __shfl_xor(m, 2, 64));
    m = fmaxf(m, __shfl_xor(m, 4, 64));
    float s = 0.f;
    #pragma unroll
    for (int i = 0; i < 8; ++i) s += expf(h[i] - m);
    s += __shfl_xor(s, 1, 64);
    s += __shfl_xor(s, 2, 64);
    s += __shfl_xor(s, 4, 64);
    const float lg = m + logf(s);
    float* op = &lout[(size_t)n * 64 + l * 8];
    float4 o0, o1;
    o0.x = h[0] - lg; o0.y = h[1] - lg; o0.z = h[2] - lg; o0.w = h[3] - lg;
    o1.x = h[4] - lg; o1.y = h[5] - lg; o1.z = h[6] - lg; o1.w = h[7] - lg;
    *reinterpret_cast<float4*>(op) = o0;
    *reinterpret_cast<float4*>(op + 4) = o1;
}

extern "C" void kernel_launch(void* const* d_in, const int* in_sizes, int n_in,
                              void* d_out, int out_size, void* d_ws, size_t ws_size,
                              hipStream_t stream) {
    const float* x   = (const float*)d_in[0];
    const int*   ei  = (const int*)d_in[1];
    const float* Wl0 = (const float*)d_in[2];
    const float* bl0 = (const float*)d_in[3];
    const float* Wr0 = (const float*)d_in[4];
    const float* Wl1 = (const float*)d_in[5];
    const float* bl1 = (const float*)d_in[6];
    const float* Wr1 = (const float*)d_in[7];
    const float* Wl2 = (const float*)d_in[8];
    const float* bl2 = (const float*)d_in[9];
    const float* Wr2 = (const float*)d_in[10];
    float* out = (float*)d_out;

    unsigned char*  Yqa = (unsigned char*)d_ws;                        // [NPAD][128] fp8
    unsigned char*  Yqb = Yqa + (size_t)NPAD * 128;                    // [NPAD][128] fp8
    unsigned short* Za  = (unsigned short*)(Yqb + (size_t)NPAD * 128); // [NPAD][128] bf16
    unsigned short* Zb  = Za + (size_t)NPAD * 128;                     // [NPAD][128] bf16
    unsigned short* Bp  = Zb + (size_t)NPAD * 128;                     // 81920
    int* rowptr = (int*)(Bp + 81920);                                  // NN+2
    int* cursor = rowptr + (NN + 2);                                   // NBK*CSTRIDE
    int* csr    = cursor + NBK * CSTRIDE;                              // NE
    unsigned int* bucket = (unsigned int*)(csr + NE);                  // NBK*BCAP

    zero_k<<<1, NBK, 0, stream>>>(cursor, rowptr);
    prep_k<<<NFB + 320, 256, 0, stream>>>(ei, cursor, bucket, Wl0, Wr0, Wl1, Wr1, Wl2, Wr2, Bp);
    mid_k<<<NBK + GB, 256, 0, stream>>>(bucket, cursor, rowptr, csr, x, Bp, Yqa, Za);
    fused_k<128><<<GB, 512, 0, stream>>>(rowptr, csr, Yqa, Za, bl0, Bp + 32768, Yqb, Zb);
    fused_k<64><<<GB, 512, 0, stream>>>(rowptr, csr, Yqb, Zb, bl1, Bp + 65536, Yqa, Za);
    gathlsm_k<<<GB, 512, 0, stream>>>(rowptr, csr, Yqa, Za, bl2, out);
}

// Round 10
// 133.629 us; speedup vs baseline: 1.1039x; 1.1039x over previous
//
#include <hip/hip_runtime.h>
#include <hip/hip_bf16.h>

#define NN 50000
#define NE 800000
#define NPAD 50048   // rows padded to multiple of 64
#define NBK 512      // coarse buckets for CSR build
#define RNG 98       // nodes per bucket (512*98 = 50176 >= NN)
#define BCAP 2560    // bucket capacity (mean 1568, +25 sigma)
#define CSTRIDE 16   // cursor padding: 1 cursor per 64B line
#define EPB 4096     // edges per block in bucket fill
#define NFB ((NE + EPB - 1) / EPB)   // 196 blocks
#define GB (NPAD / 64)               // 782 row-blocks (layer-1 GEMM)
#define GB2 (NPAD / 32)              // 1564 blocks (fused/gathlsm tiles)
#define CSRCAP2 768  // per-32-node CSR window (mean 512, +11 sigma)

typedef __attribute__((ext_vector_type(8))) short bf8;       // 8 bf16 = 4 VGPR
typedef __attribute__((ext_vector_type(4))) float f4;
typedef __attribute__((ext_vector_type(2))) float f2v;
typedef __attribute__((ext_vector_type(4))) unsigned int u4v; // 16B
typedef __attribute__((ext_vector_type(2))) unsigned int u2v; // 8B

__device__ __forceinline__ unsigned short f2bf(float f) {  // RNE
    union { float f; unsigned int u; } x; x.f = f;
    unsigned int r = x.u + 0x7fffu + ((x.u >> 16) & 1u);
    return (unsigned short)(r >> 16);
}
__device__ __forceinline__ float b2f(short s) {
    union { unsigned int u; float f; } x;
    x.u = ((unsigned int)(unsigned short)s) << 16;
    return x.f;
}
__device__ __forceinline__ unsigned char f2fp8(float v) {  // e4m3 (OCP), RNE
    return (unsigned char)(__builtin_amdgcn_cvt_pk_fp8_f32(v, v, 0, false) & 0xff);
}
__device__ __forceinline__ void acc16_fp8(float* acc, u4v v) {
    #pragma unroll
    for (int t = 0; t < 4; ++t) {
        f2v lo = __builtin_amdgcn_cvt_pk_f32_fp8((int)v[t], false);
        f2v hi = __builtin_amdgcn_cvt_pk_f32_fp8((int)v[t], true);
        acc[t * 4 + 0] += lo.x; acc[t * 4 + 1] += lo.y;
        acc[t * 4 + 2] += hi.x; acc[t * 4 + 3] += hi.y;
    }
}
__device__ __forceinline__ void acc8_fp8(float* acc, u2v v) {
    #pragma unroll
    for (int t = 0; t < 2; ++t) {
        f2v lo = __builtin_amdgcn_cvt_pk_f32_fp8((int)v[t], false);
        f2v hi = __builtin_amdgcn_cvt_pk_f32_fp8((int)v[t], true);
        acc[t * 4 + 0] += lo.x; acc[t * 4 + 1] += lo.y;
        acc[t * 4 + 2] += hi.x; acc[t * 4 + 3] += hi.y;
    }
}

// ---------------- launch 1: zero bucket cursors ----------------
__global__ void zero_k(int* __restrict__ cursor, int* __restrict__ rowptr) {
    cursor[threadIdx.x * CSTRIDE] = 0;
    if (threadIdx.x == 0) rowptr[NN] = NE;
}

// ---------------- launch 2: bucket fill (blocks 0..NFB-1) || pack weights ----------------
__global__ __launch_bounds__(256) void prep_k(const int* __restrict__ ei,
                                              int* __restrict__ cursor,
                                              unsigned int* __restrict__ bucket,
                                              const float* __restrict__ Wl0, const float* __restrict__ Wr0,
                                              const float* __restrict__ Wl1, const float* __restrict__ Wr1,
                                              const float* __restrict__ Wl2, const float* __restrict__ Wr2,
                                              unsigned short* __restrict__ Bp) {
    __shared__ unsigned int sorted[EPB];
    __shared__ unsigned short sbuck[EPB];
    __shared__ int hist[NBK], ofs[NBK], gpos[NBK], stmp[256];
    const int tid = threadIdx.x;
    if (blockIdx.x >= NFB) {
        int idx = (blockIdx.x - NFB) * 256 + tid;
        const float *Wl, *Wr;
        int Mo, local;
        unsigned short* out;
        if (idx < 32768)       { Wl = Wl0; Wr = Wr0; Mo = 128; out = Bp;         local = idx; }
        else if (idx < 65536)  { Wl = Wl1; Wr = Wr1; Mo = 128; out = Bp + 32768; local = idx - 32768; }
        else if (idx < 81920)  { Wl = Wl2; Wr = Wr2; Mo = 64;  out = Bp + 65536; local = idx - 65536; }
        else return;
        int ncol = 2 * Mo;
        int k = local / ncol, c = local % ncol;
        float v = (c < Mo) ? Wl[k * Mo + c] : Wr[k * Mo + (c - Mo)];
        int cf = c >> 4, ks = k >> 5;
        int lane = (c & 15) | (((k & 31) >> 3) << 4);
        int i = k & 7;
        out[(((cf << 2) | ks) * 64 + lane) * 8 + i] = f2bf(v);
        return;
    }
    const int e0 = blockIdx.x * EPB;
    const int n = (NE - e0) < EPB ? (NE - e0) : EPB;

    for (int i = tid; i < NBK; i += 256) hist[i] = 0;
    __syncthreads();

    unsigned int ent[EPB / 256];
    short bks[EPB / 256];
    #pragma unroll
    for (int j = 0; j < EPB / 256; ++j) {
        const int li = tid + j * 256;
        int b = -1; unsigned v = 0;
        if (li < n) {
            const int e = e0 + li;
            const int s = ei[e];
            const int d = ei[NE + e];
            b = d / RNG;
            v = (unsigned)s | ((unsigned)(d - b * RNG) << 16);
            atomicAdd(&hist[b], 1);
        }
        ent[j] = v; bks[j] = (short)b;
    }
    __syncthreads();

    const int p0 = hist[2 * tid], p1 = hist[2 * tid + 1];
    stmp[tid] = p0 + p1;
    __syncthreads();
    #pragma unroll
    for (int off = 1; off < 256; off <<= 1) {
        const int t = (tid >= off) ? stmp[tid - off] : 0;
        __syncthreads();
        stmp[tid] += t;
        __syncthreads();
    }
    const int pbase = stmp[tid] - p0 - p1;
    ofs[2 * tid] = pbase;
    ofs[2 * tid + 1] = pbase + p0;
    __syncthreads();

    for (int i = tid; i < NBK; i += 256) {
        const int c = hist[i];
        gpos[i] = c ? atomicAdd(&cursor[i * CSTRIDE], c) : 0;
    }
    for (int i = tid; i < NBK; i += 256) hist[i] = ofs[i];
    __syncthreads();
    #pragma unroll
    for (int j = 0; j < EPB / 256; ++j) {
        if (bks[j] >= 0) {
            const int r = atomicAdd(&hist[(int)bks[j]], 1);
            sorted[r] = ent[j];
            sbuck[r] = (unsigned short)bks[j];
        }
    }
    __syncthreads();
    for (int i = tid; i < n; i += 256) {
        const int b = sbuck[i];
        const int idx = gpos[b] + (i - ofs[b]);
        if (idx < BCAP) bucket[(size_t)b * BCAP + idx] = sorted[i];
    }
}

// ---------------- launch 3: csr_build (blocks 0..511) || layer-1 GEMM from fp32 x ----------------
__global__ __launch_bounds__(256) void mid_k(const unsigned int* __restrict__ bucket,
                                             const int* __restrict__ cursor,
                                             int* __restrict__ rowptr, int* __restrict__ csr,
                                             const float* __restrict__ x,
                                             const unsigned short* __restrict__ Bp,
                                             unsigned char* __restrict__ Yq,
                                             unsigned short* __restrict__ Z) {
    __shared__ unsigned int ent[BCAP];
    __shared__ int hist[RNG], lcur[RNG], sofs[NBK], stmp[256];
    const int tid = threadIdx.x;
    if (blockIdx.x < NBK) {
        const int b = blockIdx.x;
        const int c0 = cursor[(2 * tid) * CSTRIDE];
        const int c1 = cursor[(2 * tid + 1) * CSTRIDE];
        stmp[tid] = c0 + c1;
        __syncthreads();
        #pragma unroll
        for (int off = 1; off < 256; off <<= 1) {
            const int t = (tid >= off) ? stmp[tid - off] : 0;
            __syncthreads();
            stmp[tid] += t;
            __syncthreads();
        }
        const int pbase = stmp[tid] - c0 - c1;
        sofs[2 * tid] = pbase;
        sofs[2 * tid + 1] = pbase + c0;
        for (int i = tid; i < RNG; i += 256) { hist[i] = 0; lcur[i] = 0; }
        __syncthreads();

        const int sz0 = cursor[b * CSTRIDE];
        const int sz = sz0 < BCAP ? sz0 : BCAP;
        const int gbase = sofs[b];
        for (int i = tid; i < sz; i += 256) {
            unsigned v = bucket[(size_t)b * BCAP + i];
            ent[i] = v;
            atomicAdd(&hist[v >> 16], 1);
        }
        __syncthreads();
        if (tid == 0) {
            int acc = 0;
            #pragma unroll 2
            for (int i = 0; i < RNG; ++i) { int c = hist[i]; hist[i] = acc; acc += c; }
        }
        __syncthreads();
        const int n0 = b * RNG;
        for (int i = tid; i < RNG; i += 256) {
            int nn = n0 + i;
            if (nn < NN) rowptr[nn] = gbase + hist[i];
        }
        for (int i = tid; i < sz; i += 256) {
            unsigned v = ent[i];
            int dloc = v >> 16;
            int r = atomicAdd(&lcur[dloc], 1);
            csr[gbase + hist[dloc] + r] = (int)(v & 0xffffu);
        }
        return;
    }
    // ---- layer-1 dual GEMM ----
    const int wave = tid >> 6;
    const int lane = tid & 63;
    const int r0 = (blockIdx.x - NBK) * 64;

    bf8 bfr[4][4];
    const bf8* bp = reinterpret_cast<const bf8*>(Bp);
    #pragma unroll
    for (int cf = 0; cf < 4; ++cf)
        #pragma unroll
        for (int ks = 0; ks < 4; ++ks)
            bfr[cf][ks] = bp[((wave * 4 + cf) * 4 + ks) * 64 + lane];

    const int rlane = lane & 15, kc = lane >> 4;
    #pragma unroll
    for (int rf = 0; rf < 4; ++rf) {
        const int arow = r0 + rf * 16 + rlane;
        const bool ok = arow < NN;
        const float4* ap = reinterpret_cast<const float4*>(x + (size_t)arow * 128);
        bf8 afr[4];
        #pragma unroll
        for (int ks = 0; ks < 4; ++ks) {
            float4 a0 = make_float4(0.f,0.f,0.f,0.f), a1 = a0;
            if (ok) { a0 = ap[ks * 8 + kc * 2]; a1 = ap[ks * 8 + kc * 2 + 1]; }
            bf8 t;
            t[0]=(short)f2bf(a0.x); t[1]=(short)f2bf(a0.y); t[2]=(short)f2bf(a0.z); t[3]=(short)f2bf(a0.w);
            t[4]=(short)f2bf(a1.x); t[5]=(short)f2bf(a1.y); t[6]=(short)f2bf(a1.z); t[7]=(short)f2bf(a1.w);
            afr[ks] = t;
        }
        f4 acc[4];
        #pragma unroll
        for (int cf = 0; cf < 4; ++cf) acc[cf] = (f4){0.f, 0.f, 0.f, 0.f};
        #pragma unroll
        for (int ks = 0; ks < 4; ++ks)
            #pragma unroll
            for (int cf = 0; cf < 4; ++cf)
                acc[cf] = __builtin_amdgcn_mfma_f32_16x16x32_bf16(afr[ks], bfr[cf][ks], acc[cf], 0, 0, 0);
        const int orow0 = r0 + rf * 16 + (lane >> 4) * 4;
        #pragma unroll
        for (int j = 0; j < 4; ++j) {
            const int orow = orow0 + j;
            if (orow < NN) {
                #pragma unroll
                for (int cf = 0; cf < 4; ++cf) {
                    const int col = (wave * 4 + cf) * 16 + rlane;
                    const float v = acc[cf][j];
                    if (col < 128) Yq[(size_t)orow * 128 + col] = f2fp8(v);
                    else           Z[(size_t)orow * 128 + (col - 128)] = f2bf(v);
                }
            }
        }
    }
}

// ---------------- launches 4,5: fused gather+combine+ELU+GEMM (256 thr, 32 nodes) ----------------
// Phase A: 8 lanes/node, 16 fp8 cols each (one 16B load per edge); 8-edge unroll.
// Phase B: dual GEMM over 32-row tile, col-frags split across 4 waves.
template<int MOUT>
__global__ __launch_bounds__(256) void fused_k(const int* __restrict__ rowptr,
                                               const int* __restrict__ csr,
                                               const unsigned char* __restrict__ Yq_in,
                                               const unsigned short* __restrict__ Z_in,
                                               const float* __restrict__ bias,
                                               const unsigned short* __restrict__ Bp,
                                               unsigned char* __restrict__ Yq_out,
                                               unsigned short* __restrict__ Z_out) {
    constexpr int CFW = 2 * MOUT / 64;     // col-frags per wave (4 or 2)
    __shared__ int lcsr[CSRCAP2];
    __shared__ unsigned short tile[32 * 128];  // XOR-swizzled: byte ^= (row&7)<<4
    const int tid = threadIdx.x;
    const int n0 = blockIdx.x * 32;
    const int nend = (n0 + 32 > NN) ? NN : (n0 + 32);
    const int beg0 = rowptr[n0];
    const int tot = rowptr[nend] - beg0;
    const bool inlds = tot <= CSRCAP2;
    if (inlds) for (int i = tid; i < tot; i += 256) lcsr[i] = csr[beg0 + i];
    __syncthreads();

    // ---- phase A: gather ----
    const int g = tid >> 3, l = tid & 7;   // node-in-block (0..31), lane-in-node (16 cols)
    const int node = n0 + g;
    char* tbase = reinterpret_cast<char*>(tile);
    if (node < NN) {
        const int beg = rowptr[node], end = rowptr[node + 1];
        float acc[16];
        #pragma unroll
        for (int i = 0; i < 16; ++i) acc[i] = 0.f;
        int e = beg;
        for (; e + 8 <= end; e += 8) {     // 8 independent lines in flight
            int ss[8];
            #pragma unroll
            for (int j = 0; j < 8; ++j) ss[j] = inlds ? lcsr[e + j - beg0] : csr[e + j];
            u4v u[8];
            #pragma unroll
            for (int j = 0; j < 8; ++j)
                u[j] = *reinterpret_cast<const u4v*>(Yq_in + (size_t)ss[j] * 128 + l * 16);
            #pragma unroll
            for (int j = 0; j < 8; ++j) acc16_fp8(acc, u[j]);
        }
        for (; e + 4 <= end; e += 4) {
            int ss[4];
            #pragma unroll
            for (int j = 0; j < 4; ++j) ss[j] = inlds ? lcsr[e + j - beg0] : csr[e + j];
            u4v u[4];
            #pragma unroll
            for (int j = 0; j < 4; ++j)
                u[j] = *reinterpret_cast<const u4v*>(Yq_in + (size_t)ss[j] * 128 + l * 16);
            #pragma unroll
            for (int j = 0; j < 4; ++j) acc16_fp8(acc, u[j]);
        }
        for (; e < end; ++e) {
            const int s0 = inlds ? lcsr[e - beg0] : csr[e];
            acc16_fp8(acc, *reinterpret_cast<const u4v*>(Yq_in + (size_t)s0 * 128 + l * 16));
        }
        const float invd = 1.0f / fmaxf((float)(end - beg), 1.0f);
        const bf8* zp = reinterpret_cast<const bf8*>(&Z_in[(size_t)node * 128 + l * 16]);
        const float* bp = bias + l * 16;
        #pragma unroll
        for (int c8 = 0; c8 < 2; ++c8) {
            const bf8 z = zp[c8];
            bf8 o;
            #pragma unroll
            for (int i = 0; i < 8; ++i) {
                float h = acc[c8 * 8 + i] * invd + b2f(z[i]) + bp[c8 * 8 + i];
                h = h > 0.f ? h : expf(h) - 1.f;  // ELU
                o[i] = (short)f2bf(h);
            }
            const unsigned byte = (unsigned)((g * 256 + l * 32 + c8 * 16) ^ ((g & 7) << 4));
            *reinterpret_cast<bf8*>(tbase + byte) = o;
        }
    } else {
        const bf8 zz = (bf8){0,0,0,0,0,0,0,0};
        #pragma unroll
        for (int c8 = 0; c8 < 2; ++c8) {
            const unsigned byte = (unsigned)((g * 256 + l * 32 + c8 * 16) ^ ((g & 7) << 4));
            *reinterpret_cast<bf8*>(tbase + byte) = zz;
        }
    }

    // ---- phase B: dual GEMM from LDS tile (4 waves x CFW col-frags, 2 row-frags) ----
    const int wave = tid >> 6;
    const int lane = tid & 63;
    bf8 bfr[CFW][4];
    const bf8* bpf = reinterpret_cast<const bf8*>(Bp);
    #pragma unroll
    for (int cf = 0; cf < CFW; ++cf)
        #pragma unroll
        for (int ks = 0; ks < 4; ++ks)
            bfr[cf][ks] = bpf[((wave * CFW + cf) * 4 + ks) * 64 + lane];
    __syncthreads();

    const int rlane = lane & 15, kc = lane >> 4;
    #pragma unroll
    for (int rf = 0; rf < 2; ++rf) {
        const int row = rf * 16 + rlane;
        bf8 afr[4];
        #pragma unroll
        for (int ks = 0; ks < 4; ++ks) {
            const unsigned byte = (unsigned)((row * 256 + ks * 64 + kc * 16) ^ ((row & 7) << 4));
            afr[ks] = *reinterpret_cast<const bf8*>(tbase + byte);
        }
        f4 acc[CFW];
        #pragma unroll
        for (int cf = 0; cf < CFW; ++cf) acc[cf] = (f4){0.f, 0.f, 0.f, 0.f};
        #pragma unroll
        for (int ks = 0; ks < 4; ++ks)
            #pragma unroll
            for (int cf = 0; cf < CFW; ++cf)
                acc[cf] = __builtin_amdgcn_mfma_f32_16x16x32_bf16(afr[ks], bfr[cf][ks], acc[cf], 0, 0, 0);
        const int orow0 = n0 + rf * 16 + (lane >> 4) * 4;
        #pragma unroll
        for (int j = 0; j < 4; ++j) {
            const int orow = orow0 + j;
            if (orow < NN) {
                #pragma unroll
                for (int cf = 0; cf < CFW; ++cf) {
                    const int col = (wave * CFW + cf) * 16 + rlane;
                    const float v = acc[cf][j];
                    if (col < MOUT) Yq_out[(size_t)orow * MOUT + col] = f2fp8(v);
                    else            Z_out[(size_t)orow * MOUT + (col - MOUT)] = f2bf(v);
                }
            }
        }
    }
}

// ---------------- launch 6: final gather + combine + log_softmax (256 thr, 32 nodes) ----------------
__global__ __launch_bounds__(256) void gathlsm_k(const int* __restrict__ rowptr,
                                                 const int* __restrict__ csr,
                                                 const unsigned char* __restrict__ Yq2,
                                                 const unsigned short* __restrict__ Z2,
                                                 const float* __restrict__ bias,
                                                 float* __restrict__ lout) {
    __shared__ int lcsr[CSRCAP2];
    const int tid = threadIdx.x;
    const int n0 = blockIdx.x * 32;
    const int nend = (n0 + 32 > NN) ? NN : (n0 + 32);
    const int beg0 = rowptr[n0];
    const int tot = rowptr[nend] - beg0;
    const bool inlds = tot <= CSRCAP2;
    if (inlds) for (int i = tid; i < tot; i += 256) lcsr[i] = csr[beg0 + i];
    __syncthreads();

    const int g = tid >> 3, l = tid & 7;   // 32 nodes/block, 8 cols/lane
    const int n = n0 + g;
    if (n >= NN) return;
    const int beg = rowptr[n], end = rowptr[n + 1];

    float acc[8];
    #pragma unroll
    for (int i = 0; i < 8; ++i) acc[i] = 0.f;
    int e = beg;
    for (; e + 8 <= end; e += 8) {
        int ss[8];
        #pragma unroll
        for (int j = 0; j < 8; ++j) ss[j] = inlds ? lcsr[e + j - beg0] : csr[e + j];
        u2v u[8];
        #pragma unroll
        for (int j = 0; j < 8; ++j)
            u[j] = *reinterpret_cast<const u2v*>(Yq2 + (size_t)ss[j] * 64 + l * 8);
        #pragma unroll
        for (int j = 0; j < 8; ++j) acc8_fp8(acc, u[j]);
    }
    for (; e < end; ++e) {
        const int s0 = inlds ? lcsr[e - beg0] : csr[e];
        acc8_fp8(acc, *reinterpret_cast<const u2v*>(Yq2 + (size_t)s0 * 64 + l * 8));
    }
    const float inv = 1.0f / fmaxf((float)(end - beg), 1.0f);
    const bf8 z = *reinterpret_cast<const bf8*>(&Z2[(size_t)n * 64 + l * 8]);
    float h[8];
    #pragma unroll
    for (int i = 0; i < 8; ++i) h[i] = acc[i] * inv + b2f(z[i]) + bias[l * 8 + i];

    float m = h[0];
    #pragma unroll
    for (int i = 1; i < 8; ++i) m = fmaxf(m, h[i]);
    m = fmaxf(m, __shfl_xor(m, 1, 64));
    m = fmaxf(m, __shfl_xor(m, 2, 64));
    m = fmaxf(m, __shfl_xor(m, 4, 64));
    float s = 0.f;
    #pragma unroll
    for (int i = 0; i < 8; ++i) s += expf(h[i] - m);
    s += __shfl_xor(s, 1, 64);
    s += __shfl_xor(s, 2, 64);
    s += __shfl_xor(s, 4, 64);
    const float lg = m + logf(s);
    float* op = &lout[(size_t)n * 64 + l * 8];
    float4 o0, o1;
    o0.x = h[0] - lg; o0.y = h[1] - lg; o0.z = h[2] - lg; o0.w = h[3] - lg;
    o1.x = h[4] - lg; o1.y = h[5] - lg; o1.z = h[6] - lg; o1.w = h[7] - lg;
    *reinterpret_cast<float4*>(op) = o0;
    *reinterpret_cast<float4*>(op + 4) = o1;
}

extern "C" void kernel_launch(void* const* d_in, const int* in_sizes, int n_in,
                              void* d_out, int out_size, void* d_ws, size_t ws_size,
                              hipStream_t stream) {
    const float* x   = (const float*)d_in[0];
    const int*   ei  = (const int*)d_in[1];
    const float* Wl0 = (const float*)d_in[2];
    const float* bl0 = (const float*)d_in[3];
    const float* Wr0 = (const float*)d_in[4];
    const float* Wl1 = (const float*)d_in[5];
    const float* bl1 = (const float*)d_in[6];
    const float* Wr1 = (const float*)d_in[7];
    const float* Wl2 = (const float*)d_in[8];
    const float* bl2 = (const float*)d_in[9];
    const float* Wr2 = (const float*)d_in[10];
    float* out = (float*)d_out;

    unsigned char*  Yqa = (unsigned char*)d_ws;                        // [NPAD][128] fp8
    unsigned char*  Yqb = Yqa + (size_t)NPAD * 128;                    // [NPAD][128] fp8
    unsigned short* Za  = (unsigned short*)(Yqb + (size_t)NPAD * 128); // [NPAD][128] bf16
    unsigned short* Zb  = Za + (size_t)NPAD * 128;                     // [NPAD][128] bf16
    unsigned short* Bp  = Zb + (size_t)NPAD * 128;                     // 81920
    int* rowptr = (int*)(Bp + 81920);                                  // NN+2
    int* cursor = rowptr + (NN + 2);                                   // NBK*CSTRIDE
    int* csr    = cursor + NBK * CSTRIDE;                              // NE
    unsigned int* bucket = (unsigned int*)(csr + NE);                  // NBK*BCAP

    zero_k<<<1, NBK, 0, stream>>>(cursor, rowptr);
    prep_k<<<NFB + 320, 256, 0, stream>>>(ei, cursor, bucket, Wl0, Wr0, Wl1, Wr1, Wl2, Wr2, Bp);
    mid_k<<<NBK + GB, 256, 0, stream>>>(bucket, cursor, rowptr, csr, x, Bp, Yqa, Za);
    fused_k<128><<<GB2, 256, 0, stream>>>(rowptr, csr, Yqa, Za, bl0, Bp + 32768, Yqb, Zb);
    fused_k<64><<<GB2, 256, 0, stream>>>(rowptr, csr, Yqb, Zb, bl1, Bp + 65536, Yqa, Za);
    gathlsm_k<<<GB2, 256, 0, stream>>>(rowptr, csr, Yqa, Za, bl2, out);
}

// Round 11
// 125.100 us; speedup vs baseline: 1.1791x; 1.0682x over previous
//
#include <hip/hip_runtime.h>
#include <hip/hip_bf16.h>

#define NN 50000
#define NE 800000
#define NPAD 50048   // rows padded to multiple of 64
#define NBK 512      // coarse buckets for CSR build
#define RNG 98       // nodes per bucket (512*98 = 50176 >= NN)
#define BCAP 2560    // bucket capacity (mean 1568, +25 sigma)
#define CSTRIDE 16   // cursor padding: 1 cursor per 64B line
#define EPB 4096     // edges per block in bucket fill
#define NFB ((NE + EPB - 1) / EPB)   // 196 blocks
#define GB (NPAD / 64)               // 782 row-blocks (layer-1 GEMM)
#define GB2 (NPAD / 32)              // 1564 blocks (fused/gathlsm tiles)
#define CSRCAP2 768  // per-32-node CSR window (mean 512, +11 sigma)

typedef __attribute__((ext_vector_type(8))) short bf8;       // 8 bf16 = 4 VGPR
typedef __attribute__((ext_vector_type(4))) float f4;
typedef __attribute__((ext_vector_type(2))) float f2v;
typedef __attribute__((ext_vector_type(4))) unsigned int u4v; // 16B
typedef __attribute__((ext_vector_type(2))) unsigned int u2v; // 8B

__device__ __forceinline__ unsigned short f2bf(float f) {  // RNE
    union { float f; unsigned int u; } x; x.f = f;
    unsigned int r = x.u + 0x7fffu + ((x.u >> 16) & 1u);
    return (unsigned short)(r >> 16);
}
__device__ __forceinline__ float b2f(short s) {
    union { unsigned int u; float f; } x;
    x.u = ((unsigned int)(unsigned short)s) << 16;
    return x.f;
}
__device__ __forceinline__ unsigned char f2fp8(float v) {  // e4m3 (OCP), RNE
    return (unsigned char)(__builtin_amdgcn_cvt_pk_fp8_f32(v, v, 0, false) & 0xff);
}
// accumulate 16 fp8 (one 16B vector) into 8 packed f32 pairs (v_pk_add_f32)
__device__ __forceinline__ void acc16_fp8(f2v* acc, u4v v) {
    #pragma unroll
    for (int t = 0; t < 4; ++t) {
        acc[2 * t]     += __builtin_amdgcn_cvt_pk_f32_fp8((int)v[t], false);
        acc[2 * t + 1] += __builtin_amdgcn_cvt_pk_f32_fp8((int)v[t], true);
    }
}
// accumulate 8 fp8 (one 8B vector) into 4 packed f32 pairs
__device__ __forceinline__ void acc8_fp8(f2v* acc, u2v v) {
    #pragma unroll
    for (int t = 0; t < 2; ++t) {
        acc[2 * t]     += __builtin_amdgcn_cvt_pk_f32_fp8((int)v[t], false);
        acc[2 * t + 1] += __builtin_amdgcn_cvt_pk_f32_fp8((int)v[t], true);
    }
}

// ---------------- launch 1: zero bucket cursors ----------------
__global__ void zero_k(int* __restrict__ cursor, int* __restrict__ rowptr) {
    cursor[threadIdx.x * CSTRIDE] = 0;
    if (threadIdx.x == 0) rowptr[NN] = NE;
}

// ---------------- launch 2: bucket fill (blocks 0..NFB-1) || pack weights ----------------
__global__ __launch_bounds__(256) void prep_k(const int* __restrict__ ei,
                                              int* __restrict__ cursor,
                                              unsigned int* __restrict__ bucket,
                                              const float* __restrict__ Wl0, const float* __restrict__ Wr0,
                                              const float* __restrict__ Wl1, const float* __restrict__ Wr1,
                                              const float* __restrict__ Wl2, const float* __restrict__ Wr2,
                                              unsigned short* __restrict__ Bp) {
    __shared__ unsigned int sorted[EPB];
    __shared__ unsigned short sbuck[EPB];
    __shared__ int hist[NBK], ofs[NBK], gpos[NBK], stmp[256];
    const int tid = threadIdx.x;
    if (blockIdx.x >= NFB) {
        int idx = (blockIdx.x - NFB) * 256 + tid;
        const float *Wl, *Wr;
        int Mo, local;
        unsigned short* out;
        if (idx < 32768)       { Wl = Wl0; Wr = Wr0; Mo = 128; out = Bp;         local = idx; }
        else if (idx < 65536)  { Wl = Wl1; Wr = Wr1; Mo = 128; out = Bp + 32768; local = idx - 32768; }
        else if (idx < 81920)  { Wl = Wl2; Wr = Wr2; Mo = 64;  out = Bp + 65536; local = idx - 65536; }
        else return;
        int ncol = 2 * Mo;
        int k = local / ncol, c = local % ncol;
        float v = (c < Mo) ? Wl[k * Mo + c] : Wr[k * Mo + (c - Mo)];
        int cf = c >> 4, ks = k >> 5;
        int lane = (c & 15) | (((k & 31) >> 3) << 4);
        int i = k & 7;
        out[(((cf << 2) | ks) * 64 + lane) * 8 + i] = f2bf(v);
        return;
    }
    const int e0 = blockIdx.x * EPB;
    const int n = (NE - e0) < EPB ? (NE - e0) : EPB;

    for (int i = tid; i < NBK; i += 256) hist[i] = 0;
    __syncthreads();

    unsigned int ent[EPB / 256];
    short bks[EPB / 256];
    #pragma unroll
    for (int j = 0; j < EPB / 256; ++j) {
        const int li = tid + j * 256;
        int b = -1; unsigned v = 0;
        if (li < n) {
            const int e = e0 + li;
            const int s = ei[e];
            const int d = ei[NE + e];
            b = d / RNG;
            v = (unsigned)s | ((unsigned)(d - b * RNG) << 16);
            atomicAdd(&hist[b], 1);
        }
        ent[j] = v; bks[j] = (short)b;
    }
    __syncthreads();

    const int p0 = hist[2 * tid], p1 = hist[2 * tid + 1];
    stmp[tid] = p0 + p1;
    __syncthreads();
    #pragma unroll
    for (int off = 1; off < 256; off <<= 1) {
        const int t = (tid >= off) ? stmp[tid - off] : 0;
        __syncthreads();
        stmp[tid] += t;
        __syncthreads();
    }
    const int pbase = stmp[tid] - p0 - p1;
    ofs[2 * tid] = pbase;
    ofs[2 * tid + 1] = pbase + p0;
    __syncthreads();

    for (int i = tid; i < NBK; i += 256) {
        const int c = hist[i];
        gpos[i] = c ? atomicAdd(&cursor[i * CSTRIDE], c) : 0;
    }
    for (int i = tid; i < NBK; i += 256) hist[i] = ofs[i];
    __syncthreads();
    #pragma unroll
    for (int j = 0; j < EPB / 256; ++j) {
        if (bks[j] >= 0) {
            const int r = atomicAdd(&hist[(int)bks[j]], 1);
            sorted[r] = ent[j];
            sbuck[r] = (unsigned short)bks[j];
        }
    }
    __syncthreads();
    for (int i = tid; i < n; i += 256) {
        const int b = sbuck[i];
        const int idx = gpos[b] + (i - ofs[b]);
        if (idx < BCAP) bucket[(size_t)b * BCAP + idx] = sorted[i];
    }
}

// ---------------- launch 3: csr_build (blocks 0..511) || layer-1 GEMM from fp32 x ----------------
__global__ __launch_bounds__(256) void mid_k(const unsigned int* __restrict__ bucket,
                                             const int* __restrict__ cursor,
                                             int* __restrict__ rowptr, int* __restrict__ csr,
                                             const float* __restrict__ x,
                                             const unsigned short* __restrict__ Bp,
                                             unsigned char* __restrict__ Yq,
                                             unsigned short* __restrict__ Z) {
    __shared__ unsigned int ent[BCAP];
    __shared__ int hist[RNG], lcur[RNG], sofs[NBK], stmp[256];
    const int tid = threadIdx.x;
    if (blockIdx.x < NBK) {
        const int b = blockIdx.x;
        const int c0 = cursor[(2 * tid) * CSTRIDE];
        const int c1 = cursor[(2 * tid + 1) * CSTRIDE];
        stmp[tid] = c0 + c1;
        __syncthreads();
        #pragma unroll
        for (int off = 1; off < 256; off <<= 1) {
            const int t = (tid >= off) ? stmp[tid - off] : 0;
            __syncthreads();
            stmp[tid] += t;
            __syncthreads();
        }
        const int pbase = stmp[tid] - c0 - c1;
        sofs[2 * tid] = pbase;
        sofs[2 * tid + 1] = pbase + c0;
        for (int i = tid; i < RNG; i += 256) { hist[i] = 0; lcur[i] = 0; }
        __syncthreads();

        const int sz0 = cursor[b * CSTRIDE];
        const int sz = sz0 < BCAP ? sz0 : BCAP;
        const int gbase = sofs[b];
        for (int i = tid; i < sz; i += 256) {
            unsigned v = bucket[(size_t)b * BCAP + i];
            ent[i] = v;
            atomicAdd(&hist[v >> 16], 1);
        }
        __syncthreads();
        if (tid == 0) {
            int acc = 0;
            #pragma unroll 2
            for (int i = 0; i < RNG; ++i) { int c = hist[i]; hist[i] = acc; acc += c; }
        }
        __syncthreads();
        const int n0 = b * RNG;
        for (int i = tid; i < RNG; i += 256) {
            int nn = n0 + i;
            if (nn < NN) rowptr[nn] = gbase + hist[i];
        }
        for (int i = tid; i < sz; i += 256) {
            unsigned v = ent[i];
            int dloc = v >> 16;
            int r = atomicAdd(&lcur[dloc], 1);
            csr[gbase + hist[dloc] + r] = (int)(v & 0xffffu);
        }
        return;
    }
    // ---- layer-1 dual GEMM ----
    const int wave = tid >> 6;
    const int lane = tid & 63;
    const int r0 = (blockIdx.x - NBK) * 64;

    bf8 bfr[4][4];
    const bf8* bp = reinterpret_cast<const bf8*>(Bp);
    #pragma unroll
    for (int cf = 0; cf < 4; ++cf)
        #pragma unroll
        for (int ks = 0; ks < 4; ++ks)
            bfr[cf][ks] = bp[((wave * 4 + cf) * 4 + ks) * 64 + lane];

    const int rlane = lane & 15, kc = lane >> 4;
    #pragma unroll
    for (int rf = 0; rf < 4; ++rf) {
        const int arow = r0 + rf * 16 + rlane;
        const bool ok = arow < NN;
        const float4* ap = reinterpret_cast<const float4*>(x + (size_t)arow * 128);
        bf8 afr[4];
        #pragma unroll
        for (int ks = 0; ks < 4; ++ks) {
            float4 a0 = make_float4(0.f,0.f,0.f,0.f), a1 = a0;
            if (ok) { a0 = ap[ks * 8 + kc * 2]; a1 = ap[ks * 8 + kc * 2 + 1]; }
            bf8 t;
            t[0]=(short)f2bf(a0.x); t[1]=(short)f2bf(a0.y); t[2]=(short)f2bf(a0.z); t[3]=(short)f2bf(a0.w);
            t[4]=(short)f2bf(a1.x); t[5]=(short)f2bf(a1.y); t[6]=(short)f2bf(a1.z); t[7]=(short)f2bf(a1.w);
            afr[ks] = t;
        }
        f4 acc[4];
        #pragma unroll
        for (int cf = 0; cf < 4; ++cf) acc[cf] = (f4){0.f, 0.f, 0.f, 0.f};
        #pragma unroll
        for (int ks = 0; ks < 4; ++ks)
            #pragma unroll
            for (int cf = 0; cf < 4; ++cf)
                acc[cf] = __builtin_amdgcn_mfma_f32_16x16x32_bf16(afr[ks], bfr[cf][ks], acc[cf], 0, 0, 0);
        const int orow0 = r0 + rf * 16 + (lane >> 4) * 4;
        #pragma unroll
        for (int j = 0; j < 4; ++j) {
            const int orow = orow0 + j;
            if (orow < NN) {
                #pragma unroll
                for (int cf = 0; cf < 4; ++cf) {
                    const int col = (wave * 4 + cf) * 16 + rlane;
                    const float v = acc[cf][j];
                    if (col < 128) Yq[(size_t)orow * 128 + col] = f2fp8(v);
                    else           Z[(size_t)orow * 128 + (col - 128)] = f2bf(v);
                }
            }
        }
    }
}

// ---------------- launch 4: per-tile degree sort (1 wave per 32-node tile) ----------------
// perm[t*32 + rank] = local node index; rank by degree descending (ties by index).
__global__ __launch_bounds__(256) void perm_k(const int* __restrict__ rowptr,
                                              int* __restrict__ perm) {
    const int w = (int)((blockIdx.x * 256 + threadIdx.x) >> 6);  // tile id
    const int lane = threadIdx.x & 63;
    if (w >= GB2) return;
    const int n0 = w * 32;
    const int i = lane & 31;
    const int n = n0 + i;
    const int deg = (n < NN) ? (rowptr[n + 1] - rowptr[n]) : -1;
    int rank = 0;
    #pragma unroll
    for (int j = 0; j < 32; ++j) {
        const int dj = __shfl(deg, j, 64);
        rank += (dj > deg) || (dj == deg && j < i);
    }
    if (lane < 32) perm[w * 32 + rank] = i;
}

// ---------------- launches 5,6: fused gather+combine+ELU+GEMM (256 thr, 32 nodes) ----------------
// Phase A: 8 lanes/node, 16 fp8 cols each; nodes processed in degree-sorted order
// (waves get equal-degree nodes -> minimal exec-mask waste). 8-edge unroll.
// Phase B: dual GEMM over 32-row tile, col-frags split across 4 waves.
template<int MOUT>
__global__ __launch_bounds__(256) void fused_k(const int* __restrict__ rowptr,
                                               const int* __restrict__ csr,
                                               const int* __restrict__ perm,
                                               const unsigned char* __restrict__ Yq_in,
                                               const unsigned short* __restrict__ Z_in,
                                               const float* __restrict__ bias,
                                               const unsigned short* __restrict__ Bp,
                                               unsigned char* __restrict__ Yq_out,
                                               unsigned short* __restrict__ Z_out) {
    constexpr int CFW = 2 * MOUT / 64;     // col-frags per wave (4 or 2)
    __shared__ int lcsr[CSRCAP2];
    __shared__ unsigned short tile[32 * 128];  // XOR-swizzled: byte ^= (row&7)<<4
    const int tid = threadIdx.x;
    const int n0 = blockIdx.x * 32;
    const int nend = (n0 + 32 > NN) ? NN : (n0 + 32);
    const int beg0 = rowptr[n0];
    const int tot = rowptr[nend] - beg0;
    const bool inlds = tot <= CSRCAP2;
    if (inlds) for (int i = tid; i < tot; i += 256) lcsr[i] = csr[beg0 + i];
    __syncthreads();

    // ---- phase A: gather (degree-sorted node order) ----
    const int gp = perm[blockIdx.x * 32 + (tid >> 3)];  // local node slot (LDS row)
    const int l = tid & 7;                              // lane-in-node (16 cols)
    const int node = n0 + gp;
    char* tbase = reinterpret_cast<char*>(tile);
    if (node < NN) {
        const int beg = rowptr[node], end = rowptr[node + 1];
        f2v acc[8];
        #pragma unroll
        for (int i = 0; i < 8; ++i) acc[i] = (f2v){0.f, 0.f};
        int e = beg;
        for (; e + 8 <= end; e += 8) {     // 8 independent lines in flight
            int ss[8];
            #pragma unroll
            for (int j = 0; j < 8; ++j) ss[j] = inlds ? lcsr[e + j - beg0] : csr[e + j];
            u4v u[8];
            #pragma unroll
            for (int j = 0; j < 8; ++j)
                u[j] = *reinterpret_cast<const u4v*>(Yq_in + (size_t)ss[j] * 128 + l * 16);
            #pragma unroll
            for (int j = 0; j < 8; ++j) acc16_fp8(acc, u[j]);
        }
        for (; e + 4 <= end; e += 4) {
            int ss[4];
            #pragma unroll
            for (int j = 0; j < 4; ++j) ss[j] = inlds ? lcsr[e + j - beg0] : csr[e + j];
            u4v u[4];
            #pragma unroll
            for (int j = 0; j < 4; ++j)
                u[j] = *reinterpret_cast<const u4v*>(Yq_in + (size_t)ss[j] * 128 + l * 16);
            #pragma unroll
            for (int j = 0; j < 4; ++j) acc16_fp8(acc, u[j]);
        }
        for (; e < end; ++e) {
            const int s0 = inlds ? lcsr[e - beg0] : csr[e];
            acc16_fp8(acc, *reinterpret_cast<const u4v*>(Yq_in + (size_t)s0 * 128 + l * 16));
        }
        const float invd = 1.0f / fmaxf((float)(end - beg), 1.0f);
        const bf8* zp = reinterpret_cast<const bf8*>(&Z_in[(size_t)node * 128 + l * 16]);
        const float* bp = bias + l * 16;
        #pragma unroll
        for (int c8 = 0; c8 < 2; ++c8) {
            const bf8 z = zp[c8];
            bf8 o;
            #pragma unroll
            for (int i = 0; i < 8; ++i) {
                const int k = c8 * 8 + i;
                float h = acc[k >> 1][k & 1] * invd + b2f(z[i]) + bp[c8 * 8 + i];
                h = h > 0.f ? h : expf(h) - 1.f;  // ELU
                o[i] = (short)f2bf(h);
            }
            const unsigned byte = (unsigned)((gp * 256 + l * 32 + c8 * 16) ^ ((gp & 7) << 4));
            *reinterpret_cast<bf8*>(tbase + byte) = o;
        }
    } else {
        const bf8 zz = (bf8){0,0,0,0,0,0,0,0};
        #pragma unroll
        for (int c8 = 0; c8 < 2; ++c8) {
            const unsigned byte = (unsigned)((gp * 256 + l * 32 + c8 * 16) ^ ((gp & 7) << 4));
            *reinterpret_cast<bf8*>(tbase + byte) = zz;
        }
    }

    // ---- phase B: dual GEMM from LDS tile (4 waves x CFW col-frags, 2 row-frags) ----
    const int wave = tid >> 6;
    const int lane = tid & 63;
    bf8 bfr[CFW][4];
    const bf8* bpf = reinterpret_cast<const bf8*>(Bp);
    #pragma unroll
    for (int cf = 0; cf < CFW; ++cf)
        #pragma unroll
        for (int ks = 0; ks < 4; ++ks)
            bfr[cf][ks] = bpf[((wave * CFW + cf) * 4 + ks) * 64 + lane];
    __syncthreads();

    const int rlane = lane & 15, kc = lane >> 4;
    #pragma unroll
    for (int rf = 0; rf < 2; ++rf) {
        const int row = rf * 16 + rlane;
        bf8 afr[4];
        #pragma unroll
        for (int ks = 0; ks < 4; ++ks) {
            const unsigned byte = (unsigned)((row * 256 + ks * 64 + kc * 16) ^ ((row & 7) << 4));
            afr[ks] = *reinterpret_cast<const bf8*>(tbase + byte);
        }
        f4 acc[CFW];
        #pragma unroll
        for (int cf = 0; cf < CFW; ++cf) acc[cf] = (f4){0.f, 0.f, 0.f, 0.f};
        #pragma unroll
        for (int ks = 0; ks < 4; ++ks)
            #pragma unroll
            for (int cf = 0; cf < CFW; ++cf)
                acc[cf] = __builtin_amdgcn_mfma_f32_16x16x32_bf16(afr[ks], bfr[cf][ks], acc[cf], 0, 0, 0);
        const int orow0 = n0 + rf * 16 + (lane >> 4) * 4;
        #pragma unroll
        for (int j = 0; j < 4; ++j) {
            const int orow = orow0 + j;
            if (orow < NN) {
                #pragma unroll
                for (int cf = 0; cf < CFW; ++cf) {
                    const int col = (wave * CFW + cf) * 16 + rlane;
                    const float v = acc[cf][j];
                    if (col < MOUT) Yq_out[(size_t)orow * MOUT + col] = f2fp8(v);
                    else            Z_out[(size_t)orow * MOUT + (col - MOUT)] = f2bf(v);
                }
            }
        }
    }
}

// ---------------- launch 7: final gather + combine + log_softmax (256 thr, 32 nodes) ----------------
__global__ __launch_bounds__(256) void gathlsm_k(const int* __restrict__ rowptr,
                                                 const int* __restrict__ csr,
                                                 const int* __restrict__ perm,
                                                 const unsigned char* __restrict__ Yq2,
                                                 const unsigned short* __restrict__ Z2,
                                                 const float* __restrict__ bias,
                                                 float* __restrict__ lout) {
    __shared__ int lcsr[CSRCAP2];
    const int tid = threadIdx.x;
    const int n0 = blockIdx.x * 32;
    const int nend = (n0 + 32 > NN) ? NN : (n0 + 32);
    const int beg0 = rowptr[n0];
    const int tot = rowptr[nend] - beg0;
    const bool inlds = tot <= CSRCAP2;
    if (inlds) for (int i = tid; i < tot; i += 256) lcsr[i] = csr[beg0 + i];
    __syncthreads();

    const int gp = perm[blockIdx.x * 32 + (tid >> 3)];
    const int l = tid & 7;   // 8 cols/lane
    const int n = n0 + gp;
    if (n >= NN) return;
    const int beg = rowptr[n], end = rowptr[n + 1];

    f2v acc[4];
    #pragma unroll
    for (int i = 0; i < 4; ++i) acc[i] = (f2v){0.f, 0.f};
    int e = beg;
    for (; e + 8 <= end; e += 8) {
        int ss[8];
        #pragma unroll
        for (int j = 0; j < 8; ++j) ss[j] = inlds ? lcsr[e + j - beg0] : csr[e + j];
        u2v u[8];
        #pragma unroll
        for (int j = 0; j < 8; ++j)
            u[j] = *reinterpret_cast<const u2v*>(Yq2 + (size_t)ss[j] * 64 + l * 8);
        #pragma unroll
        for (int j = 0; j < 8; ++j) acc8_fp8(acc, u[j]);
    }
    for (; e < end; ++e) {
        const int s0 = inlds ? lcsr[e - beg0] : csr[e];
        acc8_fp8(acc, *reinterpret_cast<const u2v*>(Yq2 + (size_t)s0 * 64 + l * 8));
    }
    const float inv = 1.0f / fmaxf((float)(end - beg), 1.0f);
    const bf8 z = *reinterpret_cast<const bf8*>(&Z2[(size_t)n * 64 + l * 8]);
    float h[8];
    #pragma unroll
    for (int i = 0; i < 8; ++i) h[i] = acc[i >> 1][i & 1] * inv + b2f(z[i]) + bias[l * 8 + i];

    float m = h[0];
    #pragma unroll
    for (int i = 1; i < 8; ++i) m = fmaxf(m, h[i]);
    m = fmaxf(m, __shfl_xor(m, 1, 64));
    m = fmaxf(m, __shfl_xor(m, 2, 64));
    m = fmaxf(m, __shfl_xor(m, 4, 64));
    float s = 0.f;
    #pragma unroll
    for (int i = 0; i < 8; ++i) s += expf(h[i] - m);
    s += __shfl_xor(s, 1, 64);
    s += __shfl_xor(s, 2, 64);
    s += __shfl_xor(s, 4, 64);
    const float lg = m + logf(s);
    float* op = &lout[(size_t)n * 64 + l * 8];
    float4 o0, o1;
    o0.x = h[0] - lg; o0.y = h[1] - lg; o0.z = h[2] - lg; o0.w = h[3] - lg;
    o1.x = h[4] - lg; o1.y = h[5] - lg; o1.z = h[6] - lg; o1.w = h[7] - lg;
    *reinterpret_cast<float4*>(op) = o0;
    *reinterpret_cast<float4*>(op + 4) = o1;
}

extern "C" void kernel_launch(void* const* d_in, const int* in_sizes, int n_in,
                              void* d_out, int out_size, void* d_ws, size_t ws_size,
                              hipStream_t stream) {
    const float* x   = (const float*)d_in[0];
    const int*   ei  = (const int*)d_in[1];
    const float* Wl0 = (const float*)d_in[2];
    const float* bl0 = (const float*)d_in[3];
    const float* Wr0 = (const float*)d_in[4];
    const float* Wl1 = (const float*)d_in[5];
    const float* bl1 = (const float*)d_in[6];
    const float* Wr1 = (const float*)d_in[7];
    const float* Wl2 = (const float*)d_in[8];
    const float* bl2 = (const float*)d_in[9];
    const float* Wr2 = (const float*)d_in[10];
    float* out = (float*)d_out;

    unsigned char*  Yqa = (unsigned char*)d_ws;                        // [NPAD][128] fp8
    unsigned char*  Yqb = Yqa + (size_t)NPAD * 128;                    // [NPAD][128] fp8
    unsigned short* Za  = (unsigned short*)(Yqb + (size_t)NPAD * 128); // [NPAD][128] bf16
    unsigned short* Zb  = Za + (size_t)NPAD * 128;                     // [NPAD][128] bf16
    unsigned short* Bp  = Zb + (size_t)NPAD * 128;                     // 81920
    int* rowptr = (int*)(Bp + 81920);                                  // NN+2
    int* cursor = rowptr + (NN + 2);                                   // NBK*CSTRIDE
    int* csr    = cursor + NBK * CSTRIDE;                              // NE
    unsigned int* bucket = (unsigned int*)(csr + NE);                  // NBK*BCAP
    int* perm   = (int*)(bucket + (size_t)NBK * BCAP);                 // NPAD

    zero_k<<<1, NBK, 0, stream>>>(cursor, rowptr);
    prep_k<<<NFB + 320, 256, 0, stream>>>(ei, cursor, bucket, Wl0, Wr0, Wl1, Wr1, Wl2, Wr2, Bp);
    mid_k<<<NBK + GB, 256, 0, stream>>>(bucket, cursor, rowptr, csr, x, Bp, Yqa, Za);
    perm_k<<<(GB2 * 64 + 255) / 256, 256, 0, stream>>>(rowptr, perm);
    fused_k<128><<<GB2, 256, 0, stream>>>(rowptr, csr, perm, Yqa, Za, bl0, Bp + 32768, Yqb, Zb);
    fused_k<64><<<GB2, 256, 0, stream>>>(rowptr, csr, perm, Yqb, Zb, bl1, Bp + 65536, Yqa, Za);
    gathlsm_k<<<GB2, 256, 0, stream>>>(rowptr, csr, perm, Yqa, Za, bl2, out);
}